// Round 8
// baseline (296.299 us; speedup 1.0000x reference)
//
#include <hip/hip_runtime.h>
#include <stdint.h>

typedef unsigned short u16;
typedef unsigned int u32;
typedef __attribute__((ext_vector_type(8))) short short8;
typedef __attribute__((ext_vector_type(4))) float floatx4;

#define BATCH   131072
#define NA      3
#define OBS     30
#define ACTD    9
#define HID     128
#define HEADS   4
#define HD      32
#define MB      32          // 32 batch rows/block: halves per-row L2 weight traffic
#define ROWS    (MB*NA)     // 96
#define LDC     136         // padded row stride
#define LDOA    72          // oa input tile stride
#define QSCALE  0.17677669529663687f
#define NTHREADS 1024       // 16 waves

// prepacked-weight offsets in d_ws, u16 units (fragment = 64 lanes x 8 bf16)
#define OFF_WO    0
#define OFF_WOA   12288
#define OFF_WQ    36864
#define OFF_WK    53248
#define OFF_WV    69632
#define OFF_WC1   86016
#define OFF_WC2   184320
#define PRE_TOTAL 190464

#define MFMA(A,B,C) __builtin_amdgcn_mfma_f32_16x16x32_bf16((A),(B),(C),0,0,0)

__device__ __forceinline__ u16 f2bf(float f) {          // round-nearest (ties up)
    union { float f; u32 u; } v; v.f = f;
    return (u16)((v.u + 0x8000u) >> 16);
}
__device__ __forceinline__ u32 pk_bf16(float a, float b) {
    union { float f; u32 u; } x, y; x.f = a; y.f = b;
    return ((x.u + 0x8000u) >> 16) | ((y.u + 0x8000u) & 0xffff0000u);
}
__device__ __forceinline__ float lo16f(u32 w) { union { u32 u; float f; } v; v.u = w << 16; return v.f; }
__device__ __forceinline__ float hi16f(u32 w) { union { u32 u; float f; } v; v.u = w & 0xffff0000u; return v.f; }
__device__ __forceinline__ float leaky(float x) { return x >= 0.f ? x : 0.01f * x; }

// ------------- weight prepack: f32 [k][n] -> bf16 MFMA B-fragment order -------------
__global__ void prepack_kernel(const float* __restrict__ Wo,  const float* __restrict__ Woa,
                               const float* __restrict__ Wq,  const float* __restrict__ Wk,
                               const float* __restrict__ Wv,  const float* __restrict__ Wc1,
                               const float* __restrict__ Wc2, u16* __restrict__ out) {
    int i = blockIdx.x * blockDim.x + threadIdx.x;
    if (i >= PRE_TOTAL) return;
    const float* src; int K, KT, perA, base, Nsrc, Nlim; float scl = 1.f;
    if (i < OFF_WOA)      { src = Wo;  K = 30;  KT = 1; perA = 4096;  base = OFF_WO;  Nsrc = 128; Nlim = 128; }
    else if (i < OFF_WQ)  { src = Woa; K = 39;  KT = 2; perA = 8192;  base = OFF_WOA; Nsrc = 128; Nlim = 128; }
    else if (i < OFF_WK)  { src = Wq;  K = 128; KT = 4; perA = 16384; base = OFF_WQ;  Nsrc = 128; Nlim = 128; scl = QSCALE; }
    else if (i < OFF_WV)  { src = Wk;  K = 128; KT = 4; perA = 16384; base = OFF_WK;  Nsrc = 128; Nlim = 128; }
    else if (i < OFF_WC1) { src = Wv;  K = 128; KT = 4; perA = 16384; base = OFF_WV;  Nsrc = 128; Nlim = 128; }
    else if (i < OFF_WC2) { src = Wc1; K = 256; KT = 8; perA = 32768; base = OFF_WC1; Nsrc = 128; Nlim = 128; }
    else                  { src = Wc2; K = 128; KT = 4; perA = 2048;  base = OFF_WC2; Nsrc = 9;   Nlim = 9;   }
    int j = i - base;
    int agent = j / perA;
    int r = j - agent * perA;
    int e = r & 7, lane = (r >> 3) & 63, fk = r >> 9;
    int kt = fk % KT, nt = fk / KT;
    int n = nt * 16 + (lane & 15);
    int k = kt * 32 + (lane >> 4) * 8 + e;
    u16 v = 0;
    if (k < K && n < Nlim) v = f2bf(src[(agent * K + k) * Nsrc + n] * scl);
    out[i] = v;
}

// ---------------- fused forward: 1024 threads (16 waves), MB=32, 1 block/CU ----------------
// Each block reads the full 380KB weight set once; MB=32 halves the per-row L2 weight
// traffic (the dominant cost term: ~90us of the 177us MB=16 runtime was L2 weight
// streaming). Stage bodies are round-6's (batched named-scalar weight loads, no
// cross-barrier register carry); every stage gains an m-half axis over 16 waves.
__global__ __launch_bounds__(NTHREADS, 4) void fused_kernel(
    const float* __restrict__ obs, const float* __restrict__ act,
    const float* __restrict__ b_o, const float* __restrict__ b_oa,
    const float* __restrict__ bq,  const float* __restrict__ bk_, const float* __restrict__ bv,
    const float* __restrict__ bc1, const float* __restrict__ bc2,
    const u16* __restrict__ pre, float* __restrict__ out)
{
    __shared__ __align__(16) u16 s_mem[4 * ROWS * LDC];        // 104448 B -> 1 blk/CU (16 waves)
    u16* s_oemb  = s_mem;                    // o_emb (persistent)
    u16* s_oaemb = s_mem + ROWS * LDC;       // oa_emb -> attn_out
    u16* s_bufA  = s_mem + 2 * ROWS * LDC;   // oa-tile -> Q -> V
    u16* s_bufB  = s_mem + 3 * ROWS * LDC;   // K -> h

    const int tid  = threadIdx.x;
    const int wave = tid >> 6, lane = tid & 63;
    const int l15  = lane & 15, quad = lane >> 4;
    const int b0   = blockIdx.x * MB;
    const short8* preV = (const short8*)pre;

    // ---- stage 0: stage [obs|act|0] tile as packed u32 writes, layout [agent][MB][LDOA] ----
    for (int g = tid; g < ROWS * 15; g += NTHREADS) {          // obs k=0..29
        int r = g / 15, s = g - r * 15;
        int n = r / MB, bl = r - n * MB;
        const float* src = &obs[((b0 + bl) * NA + n) * OBS + 2 * s];
        *(u32*)&s_bufA[n * (MB * LDOA) + bl * LDOA + 2 * s] = pk_bf16(src[0], src[1]);
    }
    for (int g = tid; g < ROWS * 5; g += NTHREADS) {           // act k=30..38, zero k=39
        int r = g / 5, s = g - r * 5;
        int n = r / MB, bl = r - n * MB;
        const float* src = &act[((b0 + bl) * NA + n) * ACTD + 2 * s];
        float v0 = src[0], v1 = (s < 4) ? src[1] : 0.f;
        *(u32*)&s_bufA[n * (MB * LDOA) + bl * LDOA + 30 + 2 * s] = pk_bf16(v0, v1);
    }
    for (int g = tid; g < ROWS * 3; g += NTHREADS) {           // zero k=40..63 (uint4)
        int r = g / 3, s = g - r * 3;
        int n = r / MB, bl = r - n * MB;
        *(uint4*)&s_bufA[n * (MB * LDOA) + bl * LDOA + 40 + 8 * s] = make_uint4(0, 0, 0, 0);
    }
    __syncthreads();

    // ---- stage 1: embeds; wave -> (c1 = job-column 0..7, mh1 = m-half); 3 jobs/wave ----
    {
        const int c1 = wave >> 1, mh1 = wave & 1;
        const int nh2 = c1 & 3;
        const int ag0 = c1 >> 2;
        const int ag2 = (c1 + 4) >> 2;
        const int pb0 = OFF_WO / 8 + ag0 * 512;
        const int pb1 = (c1 < 4) ? (OFF_WO / 8 + 2 * 512) : (OFF_WOA / 8);
        const int kt1n = (c1 < 4) ? 1 : 2;   // job1 KT
        const int pb2 = OFF_WOA / 8 + ag2 * 1024;
        short8 w1_00 = preV[pb0 + (nh2 * 2 + 0) * 64 + lane];
        short8 w1_01 = preV[pb0 + (nh2 * 2 + 1) * 64 + lane];
        short8 w1_100 = preV[pb1 + ((nh2 * 2 + 0) * kt1n + 0) * 64 + lane];
        short8 w1_101 = preV[pb1 + ((nh2 * 2 + 0) * kt1n + 1) * 64 + lane];   // unused if kt1n==1 (valid mem)
        short8 w1_110 = preV[pb1 + ((nh2 * 2 + 1) * kt1n + 0) * 64 + lane];
        short8 w1_111 = preV[pb1 + ((nh2 * 2 + 1) * kt1n + 1) * 64 + lane];
        short8 w1_200 = preV[pb2 + ((nh2 * 2 + 0) * 2 + 0) * 64 + lane];
        short8 w1_201 = preV[pb2 + ((nh2 * 2 + 0) * 2 + 1) * 64 + lane];
        short8 w1_210 = preV[pb2 + ((nh2 * 2 + 1) * 2 + 0) * 64 + lane];
        short8 w1_211 = preV[pb2 + ((nh2 * 2 + 1) * 2 + 1) * 64 + lane];
        const float* bj0 = b_o + ag0 * HID;
        const float* bj1 = (c1 < 4) ? (b_o + 2 * HID) : b_oa;
        const float* bj2 = b_oa + ag2 * HID;
        float b1_00 = bj0[(nh2 * 2 + 0) * 16 + l15];
        float b1_01 = bj0[(nh2 * 2 + 1) * 16 + l15];
        float b1_10 = bj1[(nh2 * 2 + 0) * 16 + l15];
        float b1_11 = bj1[(nh2 * 2 + 1) * 16 + l15];
        float b1_20 = bj2[(nh2 * 2 + 0) * 16 + l15];
        float b1_21 = bj2[(nh2 * 2 + 1) * 16 + l15];
        int col0 = nh2 * 32 + l15;
        int arow = mh1 * 16 + l15;           // A-fragment batch row
        int mbase = mh1 * 16;                // C rows mbase+quad*4+rg
        {
            // job0: agent=ag0, KT=1, dst=s_oemb
            short8 a = *(const short8*)&s_bufA[ag0 * (MB * LDOA) + arow * LDOA + quad * 8];
            floatx4 acc0 = {}, acc1 = {};
            acc0 = MFMA(a, w1_00, acc0);
            acc1 = MFMA(a, w1_01, acc1);
            #pragma unroll
            for (int rg = 0; rg < 4; rg++) {
                int m = mbase + quad * 4 + rg;
                s_oemb[(m * NA + ag0) * LDC + col0]      = f2bf(leaky(acc0[rg] + b1_00));
                s_oemb[(m * NA + ag0) * LDC + col0 + 16] = f2bf(leaky(acc1[rg] + b1_01));
            }
        }
        {
            // job1: c1<4 -> (o_emb, agent2); c1>=4 -> (oa_emb, agent0)
            int ag1 = (c1 < 4) ? 2 : 0;
            short8 a0 = *(const short8*)&s_bufA[ag1 * (MB * LDOA) + arow * LDOA + quad * 8];
            floatx4 acc0 = {}, acc1 = {};
            acc0 = MFMA(a0, w1_100, acc0);
            acc1 = MFMA(a0, w1_110, acc1);
            if (c1 >= 4) {                    // wave-uniform branch
                short8 a1 = *(const short8*)&s_bufA[ag1 * (MB * LDOA) + arow * LDOA + 32 + quad * 8];
                acc0 = MFMA(a1, w1_101, acc0);
                acc1 = MFMA(a1, w1_111, acc1);
            }
            u16* dst = (c1 < 4) ? s_oemb : s_oaemb;
            #pragma unroll
            for (int rg = 0; rg < 4; rg++) {
                int m = mbase + quad * 4 + rg;
                dst[(m * NA + ag1) * LDC + col0]      = f2bf(leaky(acc0[rg] + b1_10));
                dst[(m * NA + ag1) * LDC + col0 + 16] = f2bf(leaky(acc1[rg] + b1_11));
            }
        }
        {
            // job2: oa_emb, agent=ag2, KT=2
            short8 a0 = *(const short8*)&s_bufA[ag2 * (MB * LDOA) + arow * LDOA + quad * 8];
            short8 a1 = *(const short8*)&s_bufA[ag2 * (MB * LDOA) + arow * LDOA + 32 + quad * 8];
            floatx4 acc0 = {}, acc1 = {};
            acc0 = MFMA(a0, w1_200, acc0);
            acc0 = MFMA(a1, w1_201, acc0);
            acc1 = MFMA(a0, w1_210, acc1);
            acc1 = MFMA(a1, w1_211, acc1);
            #pragma unroll
            for (int rg = 0; rg < 4; rg++) {
                int m = mbase + quad * 4 + rg;
                s_oaemb[(m * NA + ag2) * LDC + col0]      = f2bf(leaky(acc0[rg] + b1_20));
                s_oaemb[(m * NA + ag2) * LDC + col0 + 16] = f2bf(leaky(acc1[rg] + b1_21));
            }
        }
    }
    __syncthreads();

    // ---- stage 2: Q and K; wave -> (proj, nh2, m-half); 3 m-tiles each ----
    {
        const int proj = wave >> 3;          // w0-7: Q, w8-15: K
        const int nh2 = (wave >> 1) & 3;
        const int mh2 = wave & 1;
        const int pbqk = (proj ? OFF_WK : OFF_WQ) / 8;
        const float* bqk = proj ? bk_ : bq;
        const float bscl = proj ? 1.f : QSCALE;
        short8 w2_00 = preV[pbqk + ((nh2 * 2 + 0) * 4 + 0) * 64 + lane];
        short8 w2_01 = preV[pbqk + ((nh2 * 2 + 0) * 4 + 1) * 64 + lane];
        short8 w2_02 = preV[pbqk + ((nh2 * 2 + 0) * 4 + 2) * 64 + lane];
        short8 w2_03 = preV[pbqk + ((nh2 * 2 + 0) * 4 + 3) * 64 + lane];
        short8 w2_10 = preV[pbqk + ((nh2 * 2 + 1) * 4 + 0) * 64 + lane];
        short8 w2_11 = preV[pbqk + ((nh2 * 2 + 1) * 4 + 1) * 64 + lane];
        short8 w2_12 = preV[pbqk + ((nh2 * 2 + 1) * 4 + 2) * 64 + lane];
        short8 w2_13 = preV[pbqk + ((nh2 * 2 + 1) * 4 + 3) * 64 + lane];
        float b2_0 = bqk[(nh2 * 2 + 0) * 16 + l15] * bscl;
        float b2_1 = bqk[(nh2 * 2 + 1) * 16 + l15] * bscl;
        const u16* Abuf = proj ? s_oaemb : s_oemb;
        u16* dst = proj ? s_bufB : s_bufA;
        int col0 = nh2 * 32 + l15;
        for (int mt = mh2 * 3; mt < mh2 * 3 + 3; mt++) {
            short8 xa0 = *(const short8*)&Abuf[(mt * 16 + l15) * LDC + 0  + quad * 8];
            short8 xa1 = *(const short8*)&Abuf[(mt * 16 + l15) * LDC + 32 + quad * 8];
            short8 xa2 = *(const short8*)&Abuf[(mt * 16 + l15) * LDC + 64 + quad * 8];
            short8 xa3 = *(const short8*)&Abuf[(mt * 16 + l15) * LDC + 96 + quad * 8];
            floatx4 acc0 = {}, acc1 = {};
            acc0 = MFMA(xa0, w2_00, acc0); acc0 = MFMA(xa1, w2_01, acc0);
            acc0 = MFMA(xa2, w2_02, acc0); acc0 = MFMA(xa3, w2_03, acc0);
            acc1 = MFMA(xa0, w2_10, acc1); acc1 = MFMA(xa1, w2_11, acc1);
            acc1 = MFMA(xa2, w2_12, acc1); acc1 = MFMA(xa3, w2_13, acc1);
            #pragma unroll
            for (int rg = 0; rg < 4; rg++) {
                int m = mt * 16 + quad * 4 + rg;
                dst[m * LDC + col0]      = f2bf(acc0[rg] + b2_0);
                dst[m * LDC + col0 + 16] = f2bf(acc1[rg] + b2_1);
            }
        }
    }
    __syncthreads();

    // ---- stage 3a: masked softmax, off-diagonal only; probs stay in registers ----
    float2 prob = make_float2(0.f, 0.f);
    int e3 = 0, h3 = 0, n3 = 0, m30 = 0, m31 = 0;
    const bool attn_thread = (tid < MB * HEADS * NA);      // 384 threads
    if (attn_thread) {
        int r = tid;
        e3 = r / (HEADS * NA); r -= e3 * HEADS * NA; h3 = r / NA; n3 = r - h3 * NA;
        m30 = (n3 == 0) ? 1 : 0;
        m31 = (n3 == 2) ? 1 : 2;
        const uint4* qp  = (const uint4*)&s_bufA[(e3 * NA + n3) * LDC + h3 * HD];
        const uint4* kp0 = (const uint4*)&s_bufB[(e3 * NA + m30) * LDC + h3 * HD];
        const uint4* kp1 = (const uint4*)&s_bufB[(e3 * NA + m31) * LDC + h3 * HD];
        float s0 = 0.f, s1 = 0.f;
        #pragma unroll
        for (int c = 0; c < 4; c++) {
            uint4 qw = qp[c], aw = kp0[c], bw = kp1[c];
            u32 qv[4] = {qw.x, qw.y, qw.z, qw.w};
            u32 av[4] = {aw.x, aw.y, aw.z, aw.w};
            u32 bv_[4] = {bw.x, bw.y, bw.z, bw.w};
            #pragma unroll
            for (int j = 0; j < 4; j++) {
                float ql = lo16f(qv[j]), qh = hi16f(qv[j]);
                s0 += ql * lo16f(av[j]) + qh * hi16f(av[j]);
                s1 += ql * lo16f(bv_[j]) + qh * hi16f(bv_[j]);
            }
        }
        float mx = fmaxf(s0, s1);
        float p0 = __expf(s0 - mx), p1 = __expf(s1 - mx);
        float inv = 1.f / (p0 + p1);
        prob = make_float2(p0 * inv, p1 * inv);
    }
    __syncthreads();

    // ---- stage 3b: V = oa_emb @ Wv + bv ; wave -> (nt, m-half); 3 m-tiles each ----
    {
        const int nt = wave >> 1, mh3 = wave & 1;
        short8 w3_0 = preV[OFF_WV / 8 + (nt * 4 + 0) * 64 + lane];
        short8 w3_1 = preV[OFF_WV / 8 + (nt * 4 + 1) * 64 + lane];
        short8 w3_2 = preV[OFF_WV / 8 + (nt * 4 + 2) * 64 + lane];
        short8 w3_3 = preV[OFF_WV / 8 + (nt * 4 + 3) * 64 + lane];
        float b3v = bv[nt * 16 + l15];
        int colv = nt * 16 + l15;
        for (int mt = mh3 * 3; mt < mh3 * 3 + 3; mt++) {
            short8 xa0 = *(const short8*)&s_oaemb[(mt * 16 + l15) * LDC + 0  + quad * 8];
            short8 xa1 = *(const short8*)&s_oaemb[(mt * 16 + l15) * LDC + 32 + quad * 8];
            short8 xa2 = *(const short8*)&s_oaemb[(mt * 16 + l15) * LDC + 64 + quad * 8];
            short8 xa3 = *(const short8*)&s_oaemb[(mt * 16 + l15) * LDC + 96 + quad * 8];
            floatx4 acc = {};
            acc = MFMA(xa0, w3_0, acc); acc = MFMA(xa1, w3_1, acc);
            acc = MFMA(xa2, w3_2, acc); acc = MFMA(xa3, w3_3, acc);
            #pragma unroll
            for (int rg = 0; rg < 4; rg++) {
                int m = mt * 16 + quad * 4 + rg;
                s_bufA[m * LDC + colv] = f2bf(acc[rg] + b3v);
            }
        }
    }
    __syncthreads();

    // ---- stage 3c: attn_out = probs @ V (probs from registers) ----
    if (attn_thread) {
        const uint4* v0p = (const uint4*)&s_bufA[(e3 * NA + m30) * LDC + h3 * HD];
        const uint4* v1p = (const uint4*)&s_bufA[(e3 * NA + m31) * LDC + h3 * HD];
        uint4* dst = (uint4*)&s_oaemb[(e3 * NA + n3) * LDC + h3 * HD];
        #pragma unroll
        for (int c = 0; c < 4; c++) {
            uint4 aw = v0p[c], bw = v1p[c], ow;
            u32 av[4] = {aw.x, aw.y, aw.z, aw.w};
            u32 bv_[4] = {bw.x, bw.y, bw.z, bw.w};
            u32 ov[4];
            #pragma unroll
            for (int j = 0; j < 4; j++) {
                float lo = prob.x * lo16f(av[j]) + prob.y * lo16f(bv_[j]);
                float hi = prob.x * hi16f(av[j]) + prob.y * hi16f(bv_[j]);
                ov[j] = pk_bf16(lo, hi);
            }
            ow.x = ov[0]; ow.y = ov[1]; ow.z = ov[2]; ow.w = ov[3];
            dst[c] = ow;
        }
    }
    __syncthreads();

    // ---- stage 4: critic layer 1; wave -> (nt, m-half); 3 agents each, 8 frags/agent ----
    {
        const int nt4 = wave >> 1, mh4 = wave & 1;
        int colc = nt4 * 16 + l15;
        int arow = mh4 * 16 + l15;
        int mbase = mh4 * 16;
        float b4_0 = bc1[0 * HID + nt4 * 16 + l15];
        float b4_1 = bc1[1 * HID + nt4 * 16 + l15];
        float b4_2 = bc1[2 * HID + nt4 * 16 + l15];
        // agent 0
        {
            short8 w0 = preV[OFF_WC1 / 8 + 0 * 4096 + (nt4 * 8 + 0) * 64 + lane];
            short8 w1 = preV[OFF_WC1 / 8 + 0 * 4096 + (nt4 * 8 + 1) * 64 + lane];
            short8 w2 = preV[OFF_WC1 / 8 + 0 * 4096 + (nt4 * 8 + 2) * 64 + lane];
            short8 w3 = preV[OFF_WC1 / 8 + 0 * 4096 + (nt4 * 8 + 3) * 64 + lane];
            short8 w4 = preV[OFF_WC1 / 8 + 0 * 4096 + (nt4 * 8 + 4) * 64 + lane];
            short8 w5 = preV[OFF_WC1 / 8 + 0 * 4096 + (nt4 * 8 + 5) * 64 + lane];
            short8 w6 = preV[OFF_WC1 / 8 + 0 * 4096 + (nt4 * 8 + 6) * 64 + lane];
            short8 w7 = preV[OFF_WC1 / 8 + 0 * 4096 + (nt4 * 8 + 7) * 64 + lane];
            floatx4 acc = {};
            short8 a;
            a = *(const short8*)&s_oemb [(arow * NA + 0) * LDC + 0  + quad * 8]; acc = MFMA(a, w0, acc);
            a = *(const short8*)&s_oemb [(arow * NA + 0) * LDC + 32 + quad * 8]; acc = MFMA(a, w1, acc);
            a = *(const short8*)&s_oemb [(arow * NA + 0) * LDC + 64 + quad * 8]; acc = MFMA(a, w2, acc);
            a = *(const short8*)&s_oemb [(arow * NA + 0) * LDC + 96 + quad * 8]; acc = MFMA(a, w3, acc);
            a = *(const short8*)&s_oaemb[(arow * NA + 0) * LDC + 0  + quad * 8]; acc = MFMA(a, w4, acc);
            a = *(const short8*)&s_oaemb[(arow * NA + 0) * LDC + 32 + quad * 8]; acc = MFMA(a, w5, acc);
            a = *(const short8*)&s_oaemb[(arow * NA + 0) * LDC + 64 + quad * 8]; acc = MFMA(a, w6, acc);
            a = *(const short8*)&s_oaemb[(arow * NA + 0) * LDC + 96 + quad * 8]; acc = MFMA(a, w7, acc);
            #pragma unroll
            for (int rg = 0; rg < 4; rg++) {
                int m = mbase + quad * 4 + rg;
                s_bufB[(m * NA + 0) * LDC + colc] = f2bf(leaky(acc[rg] + b4_0));
            }
        }
        // agent 1
        {
            short8 w0 = preV[OFF_WC1 / 8 + 1 * 4096 + (nt4 * 8 + 0) * 64 + lane];
            short8 w1 = preV[OFF_WC1 / 8 + 1 * 4096 + (nt4 * 8 + 1) * 64 + lane];
            short8 w2 = preV[OFF_WC1 / 8 + 1 * 4096 + (nt4 * 8 + 2) * 64 + lane];
            short8 w3 = preV[OFF_WC1 / 8 + 1 * 4096 + (nt4 * 8 + 3) * 64 + lane];
            short8 w4 = preV[OFF_WC1 / 8 + 1 * 4096 + (nt4 * 8 + 4) * 64 + lane];
            short8 w5 = preV[OFF_WC1 / 8 + 1 * 4096 + (nt4 * 8 + 5) * 64 + lane];
            short8 w6 = preV[OFF_WC1 / 8 + 1 * 4096 + (nt4 * 8 + 6) * 64 + lane];
            short8 w7 = preV[OFF_WC1 / 8 + 1 * 4096 + (nt4 * 8 + 7) * 64 + lane];
            floatx4 acc = {};
            short8 a;
            a = *(const short8*)&s_oemb [(arow * NA + 1) * LDC + 0  + quad * 8]; acc = MFMA(a, w0, acc);
            a = *(const short8*)&s_oemb [(arow * NA + 1) * LDC + 32 + quad * 8]; acc = MFMA(a, w1, acc);
            a = *(const short8*)&s_oemb [(arow * NA + 1) * LDC + 64 + quad * 8]; acc = MFMA(a, w2, acc);
            a = *(const short8*)&s_oemb [(arow * NA + 1) * LDC + 96 + quad * 8]; acc = MFMA(a, w3, acc);
            a = *(const short8*)&s_oaemb[(arow * NA + 1) * LDC + 0  + quad * 8]; acc = MFMA(a, w4, acc);
            a = *(const short8*)&s_oaemb[(arow * NA + 1) * LDC + 32 + quad * 8]; acc = MFMA(a, w5, acc);
            a = *(const short8*)&s_oaemb[(arow * NA + 1) * LDC + 64 + quad * 8]; acc = MFMA(a, w6, acc);
            a = *(const short8*)&s_oaemb[(arow * NA + 1) * LDC + 96 + quad * 8]; acc = MFMA(a, w7, acc);
            #pragma unroll
            for (int rg = 0; rg < 4; rg++) {
                int m = mbase + quad * 4 + rg;
                s_bufB[(m * NA + 1) * LDC + colc] = f2bf(leaky(acc[rg] + b4_1));
            }
        }
        // agent 2
        {
            short8 w0 = preV[OFF_WC1 / 8 + 2 * 4096 + (nt4 * 8 + 0) * 64 + lane];
            short8 w1 = preV[OFF_WC1 / 8 + 2 * 4096 + (nt4 * 8 + 1) * 64 + lane];
            short8 w2 = preV[OFF_WC1 / 8 + 2 * 4096 + (nt4 * 8 + 2) * 64 + lane];
            short8 w3 = preV[OFF_WC1 / 8 + 2 * 4096 + (nt4 * 8 + 3) * 64 + lane];
            short8 w4 = preV[OFF_WC1 / 8 + 2 * 4096 + (nt4 * 8 + 4) * 64 + lane];
            short8 w5 = preV[OFF_WC1 / 8 + 2 * 4096 + (nt4 * 8 + 5) * 64 + lane];
            short8 w6 = preV[OFF_WC1 / 8 + 2 * 4096 + (nt4 * 8 + 6) * 64 + lane];
            short8 w7 = preV[OFF_WC1 / 8 + 2 * 4096 + (nt4 * 8 + 7) * 64 + lane];
            floatx4 acc = {};
            short8 a;
            a = *(const short8*)&s_oemb [(arow * NA + 2) * LDC + 0  + quad * 8]; acc = MFMA(a, w0, acc);
            a = *(const short8*)&s_oemb [(arow * NA + 2) * LDC + 32 + quad * 8]; acc = MFMA(a, w1, acc);
            a = *(const short8*)&s_oemb [(arow * NA + 2) * LDC + 64 + quad * 8]; acc = MFMA(a, w2, acc);
            a = *(const short8*)&s_oemb [(arow * NA + 2) * LDC + 96 + quad * 8]; acc = MFMA(a, w3, acc);
            a = *(const short8*)&s_oaemb[(arow * NA + 2) * LDC + 0  + quad * 8]; acc = MFMA(a, w4, acc);
            a = *(const short8*)&s_oaemb[(arow * NA + 2) * LDC + 32 + quad * 8]; acc = MFMA(a, w5, acc);
            a = *(const short8*)&s_oaemb[(arow * NA + 2) * LDC + 64 + quad * 8]; acc = MFMA(a, w6, acc);
            a = *(const short8*)&s_oaemb[(arow * NA + 2) * LDC + 96 + quad * 8]; acc = MFMA(a, w7, acc);
            #pragma unroll
            for (int rg = 0; rg < 4; rg++) {
                int m = mbase + quad * 4 + rg;
                s_bufB[(m * NA + 2) * LDC + colc] = f2bf(leaky(acc[rg] + b4_2));
            }
        }
    }
    __syncthreads();

    // ---- stage 5: critic layer 2 -> q_values, f32 out; waves 0-5: (agent, m-half) ----
    if (wave < 2 * NA) {
        int agent = wave >> 1, mh5 = wave & 1;
        int arow = mh5 * 16 + l15;
        short8 w5_0 = preV[OFF_WC2 / 8 + agent * 256 + 0 * 64 + lane];
        short8 w5_1 = preV[OFF_WC2 / 8 + agent * 256 + 1 * 64 + lane];
        short8 w5_2 = preV[OFF_WC2 / 8 + agent * 256 + 2 * 64 + lane];
        short8 w5_3 = preV[OFF_WC2 / 8 + agent * 256 + 3 * 64 + lane];
        floatx4 acc = {};
        short8 a;
        a = *(const short8*)&s_bufB[(arow * NA + agent) * LDC + 0  + quad * 8]; acc = MFMA(a, w5_0, acc);
        a = *(const short8*)&s_bufB[(arow * NA + agent) * LDC + 32 + quad * 8]; acc = MFMA(a, w5_1, acc);
        a = *(const short8*)&s_bufB[(arow * NA + agent) * LDC + 64 + quad * 8]; acc = MFMA(a, w5_2, acc);
        a = *(const short8*)&s_bufB[(arow * NA + agent) * LDC + 96 + quad * 8]; acc = MFMA(a, w5_3, acc);
        if (l15 < ACTD) {
            float b5v = bc2[agent * ACTD + l15];
            #pragma unroll
            for (int rg = 0; rg < 4; rg++) {
                int m = mh5 * 16 + quad * 4 + rg;
                out[((b0 + m) * NA + agent) * ACTD + l15] = acc[rg] + b5v;
            }
        }
    }
}

extern "C" void kernel_launch(void* const* d_in, const int* in_sizes, int n_in,
                              void* d_out, int out_size, void* d_ws, size_t ws_size,
                              hipStream_t stream) {
    const float* obs = (const float*)d_in[0];
    const float* act = (const float*)d_in[1];
    const float* Wo  = (const float*)d_in[2];
    const float* bo  = (const float*)d_in[3];
    const float* Woa = (const float*)d_in[4];
    const float* boa = (const float*)d_in[5];
    const float* Wq  = (const float*)d_in[6];
    const float* bq  = (const float*)d_in[7];
    const float* Wk  = (const float*)d_in[8];
    const float* bk  = (const float*)d_in[9];
    const float* Wv  = (const float*)d_in[10];
    const float* bv  = (const float*)d_in[11];
    const float* Wc1 = (const float*)d_in[12];
    const float* bc1 = (const float*)d_in[13];
    const float* Wc2 = (const float*)d_in[14];
    const float* bc2 = (const float*)d_in[15];
    u16* pre = (u16*)d_ws;   // needs 380928 B of workspace

    prepack_kernel<<<(PRE_TOTAL + 255) / 256, 256, 0, stream>>>(Wo, Woa, Wq, Wk, Wv, Wc1, Wc2, pre);
    fused_kernel<<<BATCH / MB, NTHREADS, 0, stream>>>(obs, act, bo, boa, bq, bk, bv, bc1, bc2, pre,
                                                      (float*)d_out);
}

// Round 10
// 257.881 us; speedup vs baseline: 1.1490x; 1.1490x over previous
//
#include <hip/hip_runtime.h>
#include <stdint.h>

typedef unsigned short u16;
typedef unsigned int u32;
typedef __attribute__((ext_vector_type(8))) short short8;
typedef __attribute__((ext_vector_type(4))) float floatx4;

#define BATCH   131072
#define NA      3
#define OBS     30
#define ACTD    9
#define HID     128
#define HEADS   4
#define HD      32
#define MB      16
#define ROWS    (MB*NA)     // 48
#define LDC     136         // padded row stride
#define LDOA    72          // oa input tile stride
#define QSCALE  0.17677669529663687f
#define NTHREADS 512

// prepacked-weight offsets in d_ws, u16 units (fragment = 64 lanes x 8 bf16)
#define OFF_WO    0
#define OFF_WOA   12288
#define OFF_WQ    36864
#define OFF_WK    53248
#define OFF_WV    69632
#define OFF_WC1   86016
#define OFF_WC2   184320
#define PRE_TOTAL 190464

#define MFMA(A,B,C) __builtin_amdgcn_mfma_f32_16x16x32_bf16((A),(B),(C),0,0,0)

__device__ __forceinline__ u16 f2bf(float f) {          // round-nearest (ties up)
    union { float f; u32 u; } v; v.f = f;
    return (u16)((v.u + 0x8000u) >> 16);
}
__device__ __forceinline__ u32 pk_bf16(float a, float b) {
    union { float f; u32 u; } x, y; x.f = a; y.f = b;
    return ((x.u + 0x8000u) >> 16) | ((y.u + 0x8000u) & 0xffff0000u);
}
__device__ __forceinline__ float lo16f(u32 w) { union { u32 u; float f; } v; v.u = w << 16; return v.f; }
__device__ __forceinline__ float hi16f(u32 w) { union { u32 u; float f; } v; v.u = w & 0xffff0000u; return v.f; }
__device__ __forceinline__ float leaky(float x) { return x >= 0.f ? x : 0.01f * x; }

// ------------- weight prepack: f32 [k][n] -> bf16 MFMA B-fragment order -------------
__global__ void prepack_kernel(const float* __restrict__ Wo,  const float* __restrict__ Woa,
                               const float* __restrict__ Wq,  const float* __restrict__ Wk,
                               const float* __restrict__ Wv,  const float* __restrict__ Wc1,
                               const float* __restrict__ Wc2, u16* __restrict__ out) {
    int i = blockIdx.x * blockDim.x + threadIdx.x;
    if (i >= PRE_TOTAL) return;
    const float* src; int K, KT, perA, base, Nsrc, Nlim; float scl = 1.f;
    if (i < OFF_WOA)      { src = Wo;  K = 30;  KT = 1; perA = 4096;  base = OFF_WO;  Nsrc = 128; Nlim = 128; }
    else if (i < OFF_WQ)  { src = Woa; K = 39;  KT = 2; perA = 8192;  base = OFF_WOA; Nsrc = 128; Nlim = 128; }
    else if (i < OFF_WK)  { src = Wq;  K = 128; KT = 4; perA = 16384; base = OFF_WQ;  Nsrc = 128; Nlim = 128; scl = QSCALE; }
    else if (i < OFF_WV)  { src = Wk;  K = 128; KT = 4; perA = 16384; base = OFF_WK;  Nsrc = 128; Nlim = 128; }
    else if (i < OFF_WC1) { src = Wv;  K = 128; KT = 4; perA = 16384; base = OFF_WV;  Nsrc = 128; Nlim = 128; }
    else if (i < OFF_WC2) { src = Wc1; K = 256; KT = 8; perA = 32768; base = OFF_WC1; Nsrc = 128; Nlim = 128; }
    else                  { src = Wc2; K = 128; KT = 4; perA = 2048;  base = OFF_WC2; Nsrc = 9;   Nlim = 9;   }
    int j = i - base;
    int agent = j / perA;
    int r = j - agent * perA;
    int e = r & 7, lane = (r >> 3) & 63, fk = r >> 9;
    int kt = fk % KT, nt = fk / KT;
    int n = nt * 16 + (lane & 15);
    int k = kt * 32 + (lane >> 4) * 8 + e;
    u16 v = 0;
    if (k < K && n < Nlim) v = f2bf(src[(agent * K + k) * Nsrc + n] * scl);
    out[i] = v;
}

// ---------------- fused forward: 512 threads (8 waves), 3 blocks/CU -> 24 waves/CU ----------------
// Round-6 verified structure (batched within-stage weight loads, no cross-barrier reg
// carry) + 384-thread attention: each (e,h,n) attention job is split across 2
// lane-adjacent threads (16 cols each), scores combined with one __shfl_xor(.,1).
// Halves the serial span of the two scalar attention phases (waves 0-5 active vs 0-2).
__global__ __launch_bounds__(NTHREADS, 6) void fused_kernel(
    const float* __restrict__ obs, const float* __restrict__ act,
    const float* __restrict__ b_o, const float* __restrict__ b_oa,
    const float* __restrict__ bq,  const float* __restrict__ bk_, const float* __restrict__ bv,
    const float* __restrict__ bc1, const float* __restrict__ bc2,
    const u16* __restrict__ pre, float* __restrict__ out)
{
    __shared__ __align__(16) u16 s_mem[4 * ROWS * LDC];        // 52224 B -> 3 blk/CU
    u16* s_oemb  = s_mem;                    // o_emb (persistent)
    u16* s_oaemb = s_mem + ROWS * LDC;       // oa_emb -> attn_out
    u16* s_bufA  = s_mem + 2 * ROWS * LDC;   // oa-tile -> Q -> V
    u16* s_bufB  = s_mem + 3 * ROWS * LDC;   // K -> h

    const int tid  = threadIdx.x;
    const int wave = tid >> 6, lane = tid & 63;
    const int l15  = lane & 15, quad = lane >> 4;
    const int b0   = blockIdx.x * MB;
    const short8* preV = (const short8*)pre;

    const int nh2 = wave & 3;                // shared n-tile-pair index for stage-1 jobs & stage 2
    const int ag0 = wave >> 2;
    const int ag2 = (wave + 4) >> 2;
    const int pb0 = OFF_WO / 8 + ag0 * 512;
    const int pb1 = (wave < 4) ? (OFF_WO / 8 + 2 * 512) : (OFF_WOA / 8);
    const int kt1n = (wave < 4) ? 1 : 2;     // job1 KT
    const int pb2 = OFF_WOA / 8 + ag2 * 1024;
    const int proj = wave >> 2;              // w0-3: Q, w4-7: K

    // ---- stage 0: stage [obs|act|0] tile as packed u32 writes, layout [agent][MB][LDOA] ----
    for (int g = tid; g < ROWS * 15; g += NTHREADS) {          // obs k=0..29
        int r = g / 15, s = g - r * 15;
        int n = r / MB, bl = r - n * MB;
        const float* src = &obs[((b0 + bl) * NA + n) * OBS + 2 * s];
        *(u32*)&s_bufA[n * (MB * LDOA) + bl * LDOA + 2 * s] = pk_bf16(src[0], src[1]);
    }
    for (int g = tid; g < ROWS * 5; g += NTHREADS) {           // act k=30..38, zero k=39
        int r = g / 5, s = g - r * 5;
        int n = r / MB, bl = r - n * MB;
        const float* src = &act[((b0 + bl) * NA + n) * ACTD + 2 * s];
        float v0 = src[0], v1 = (s < 4) ? src[1] : 0.f;
        *(u32*)&s_bufA[n * (MB * LDOA) + bl * LDOA + 30 + 2 * s] = pk_bf16(v0, v1);
    }
    for (int g = tid; g < ROWS * 3; g += NTHREADS) {           // zero k=40..63 (uint4)
        int r = g / 3, s = g - r * 3;
        int n = r / MB, bl = r - n * MB;
        *(uint4*)&s_bufA[n * (MB * LDOA) + bl * LDOA + 40 + 8 * s] = make_uint4(0, 0, 0, 0);
    }
    __syncthreads();

    // ---- stage 1: batched weight loads (10 frags, issued together), then 3 jobs/wave ----
    {
        short8 w1_00 = preV[pb0 + (nh2 * 2 + 0) * 64 + lane];
        short8 w1_01 = preV[pb0 + (nh2 * 2 + 1) * 64 + lane];
        short8 w1_100 = preV[pb1 + ((nh2 * 2 + 0) * kt1n + 0) * 64 + lane];
        short8 w1_101 = preV[pb1 + ((nh2 * 2 + 0) * kt1n + 1) * 64 + lane];   // unused if kt1n==1 (valid mem)
        short8 w1_110 = preV[pb1 + ((nh2 * 2 + 1) * kt1n + 0) * 64 + lane];
        short8 w1_111 = preV[pb1 + ((nh2 * 2 + 1) * kt1n + 1) * 64 + lane];
        short8 w1_200 = preV[pb2 + ((nh2 * 2 + 0) * 2 + 0) * 64 + lane];
        short8 w1_201 = preV[pb2 + ((nh2 * 2 + 0) * 2 + 1) * 64 + lane];
        short8 w1_210 = preV[pb2 + ((nh2 * 2 + 1) * 2 + 0) * 64 + lane];
        short8 w1_211 = preV[pb2 + ((nh2 * 2 + 1) * 2 + 1) * 64 + lane];
        const float* bj0 = b_o + ag0 * HID;
        const float* bj1 = (wave < 4) ? (b_o + 2 * HID) : b_oa;
        const float* bj2 = b_oa + ag2 * HID;
        float b1_00 = bj0[(nh2 * 2 + 0) * 16 + l15];
        float b1_01 = bj0[(nh2 * 2 + 1) * 16 + l15];
        float b1_10 = bj1[(nh2 * 2 + 0) * 16 + l15];
        float b1_11 = bj1[(nh2 * 2 + 1) * 16 + l15];
        float b1_20 = bj2[(nh2 * 2 + 0) * 16 + l15];
        float b1_21 = bj2[(nh2 * 2 + 1) * 16 + l15];
        int col0 = nh2 * 32 + l15;
        {
            // job0: agent=ag0, KT=1, dst=s_oemb
            short8 a = *(const short8*)&s_bufA[ag0 * (MB * LDOA) + l15 * LDOA + quad * 8];
            floatx4 acc0 = {}, acc1 = {};
            acc0 = MFMA(a, w1_00, acc0);
            acc1 = MFMA(a, w1_01, acc1);
            #pragma unroll
            for (int rg = 0; rg < 4; rg++) {
                int m = quad * 4 + rg;
                s_oemb[(m * NA + ag0) * LDC + col0]      = f2bf(leaky(acc0[rg] + b1_00));
                s_oemb[(m * NA + ag0) * LDC + col0 + 16] = f2bf(leaky(acc1[rg] + b1_01));
            }
        }
        {
            // job1: wave<4 -> (o_emb, agent2); wave>=4 -> (oa_emb, agent0)
            int ag1 = (wave < 4) ? 2 : 0;
            short8 a0 = *(const short8*)&s_bufA[ag1 * (MB * LDOA) + l15 * LDOA + quad * 8];
            floatx4 acc0 = {}, acc1 = {};
            acc0 = MFMA(a0, w1_100, acc0);
            acc1 = MFMA(a0, w1_110, acc1);
            if (wave >= 4) {                      // wave-uniform branch
                short8 a1 = *(const short8*)&s_bufA[ag1 * (MB * LDOA) + l15 * LDOA + 32 + quad * 8];
                acc0 = MFMA(a1, w1_101, acc0);
                acc1 = MFMA(a1, w1_111, acc1);
            }
            u16* dst = (wave < 4) ? s_oemb : s_oaemb;
            #pragma unroll
            for (int rg = 0; rg < 4; rg++) {
                int m = quad * 4 + rg;
                dst[(m * NA + ag1) * LDC + col0]      = f2bf(leaky(acc0[rg] + b1_10));
                dst[(m * NA + ag1) * LDC + col0 + 16] = f2bf(leaky(acc1[rg] + b1_11));
            }
        }
        {
            // job2: oa_emb, agent=ag2, KT=2
            short8 a0 = *(const short8*)&s_bufA[ag2 * (MB * LDOA) + l15 * LDOA + quad * 8];
            short8 a1 = *(const short8*)&s_bufA[ag2 * (MB * LDOA) + l15 * LDOA + 32 + quad * 8];
            floatx4 acc0 = {}, acc1 = {};
            acc0 = MFMA(a0, w1_200, acc0);
            acc0 = MFMA(a1, w1_201, acc0);
            acc1 = MFMA(a0, w1_210, acc1);
            acc1 = MFMA(a1, w1_211, acc1);
            #pragma unroll
            for (int rg = 0; rg < 4; rg++) {
                int m = quad * 4 + rg;
                s_oaemb[(m * NA + ag2) * LDC + col0]      = f2bf(leaky(acc0[rg] + b1_20));
                s_oaemb[(m * NA + ag2) * LDC + col0 + 16] = f2bf(leaky(acc1[rg] + b1_21));
            }
        }
    }
    __syncthreads();

    // ---- stage 2: batched loads (8 frags), then Q (scale folded into Wq) and K ----
    {
        const int pbqk = (proj ? OFF_WK : OFF_WQ) / 8;
        const float* bqk = proj ? bk_ : bq;
        const float bscl = proj ? 1.f : QSCALE;
        short8 w2_00 = preV[pbqk + ((nh2 * 2 + 0) * 4 + 0) * 64 + lane];
        short8 w2_01 = preV[pbqk + ((nh2 * 2 + 0) * 4 + 1) * 64 + lane];
        short8 w2_02 = preV[pbqk + ((nh2 * 2 + 0) * 4 + 2) * 64 + lane];
        short8 w2_03 = preV[pbqk + ((nh2 * 2 + 0) * 4 + 3) * 64 + lane];
        short8 w2_10 = preV[pbqk + ((nh2 * 2 + 1) * 4 + 0) * 64 + lane];
        short8 w2_11 = preV[pbqk + ((nh2 * 2 + 1) * 4 + 1) * 64 + lane];
        short8 w2_12 = preV[pbqk + ((nh2 * 2 + 1) * 4 + 2) * 64 + lane];
        short8 w2_13 = preV[pbqk + ((nh2 * 2 + 1) * 4 + 3) * 64 + lane];
        float b2_0 = bqk[(nh2 * 2 + 0) * 16 + l15] * bscl;
        float b2_1 = bqk[(nh2 * 2 + 1) * 16 + l15] * bscl;
        const u16* Abuf = proj ? s_oaemb : s_oemb;
        u16* dst = proj ? s_bufB : s_bufA;
        int col0 = nh2 * 32 + l15;
        for (int mt = 0; mt < 3; mt++) {
            short8 xa0 = *(const short8*)&Abuf[(mt * 16 + l15) * LDC + 0  + quad * 8];
            short8 xa1 = *(const short8*)&Abuf[(mt * 16 + l15) * LDC + 32 + quad * 8];
            short8 xa2 = *(const short8*)&Abuf[(mt * 16 + l15) * LDC + 64 + quad * 8];
            short8 xa3 = *(const short8*)&Abuf[(mt * 16 + l15) * LDC + 96 + quad * 8];
            floatx4 acc0 = {}, acc1 = {};
            acc0 = MFMA(xa0, w2_00, acc0); acc0 = MFMA(xa1, w2_01, acc0);
            acc0 = MFMA(xa2, w2_02, acc0); acc0 = MFMA(xa3, w2_03, acc0);
            acc1 = MFMA(xa0, w2_10, acc1); acc1 = MFMA(xa1, w2_11, acc1);
            acc1 = MFMA(xa2, w2_12, acc1); acc1 = MFMA(xa3, w2_13, acc1);
            #pragma unroll
            for (int rg = 0; rg < 4; rg++) {
                int m = mt * 16 + quad * 4 + rg;
                dst[m * LDC + col0]      = f2bf(acc0[rg] + b2_0);
                dst[m * LDC + col0 + 16] = f2bf(acc1[rg] + b2_1);
            }
        }
    }
    __syncthreads();

    // ---- stage 3a: masked softmax, 384 threads (2 per job, 16 cols each, shfl-combine) ----
    float2 prob = make_float2(0.f, 0.f);
    int e3 = 0, h3 = 0, n3 = 0, m30 = 0, m31 = 0, half3 = 0;
    const bool attn_thread = (tid < 2 * MB * HEADS * NA);      // 384 threads, waves 0-5
    if (attn_thread) {
        int job = tid >> 1;
        half3 = tid & 1;
        int r = job;
        e3 = r / (HEADS * NA); r -= e3 * HEADS * NA; h3 = r / NA; n3 = r - h3 * NA;
        m30 = (n3 == 0) ? 1 : 0;
        m31 = (n3 == 2) ? 1 : 2;
        const int co = h3 * HD + half3 * 16;   // this thread's 16-col half (16B aligned)
        const uint4* qp  = (const uint4*)&s_bufA[(e3 * NA + n3) * LDC + co];
        const uint4* kp0 = (const uint4*)&s_bufB[(e3 * NA + m30) * LDC + co];
        const uint4* kp1 = (const uint4*)&s_bufB[(e3 * NA + m31) * LDC + co];
        float s0 = 0.f, s1 = 0.f;
        #pragma unroll
        for (int c = 0; c < 2; c++) {
            uint4 qw = qp[c], aw = kp0[c], bw = kp1[c];
            u32 qv[4] = {qw.x, qw.y, qw.z, qw.w};
            u32 av[4] = {aw.x, aw.y, aw.z, aw.w};
            u32 bv_[4] = {bw.x, bw.y, bw.z, bw.w};
            #pragma unroll
            for (int j = 0; j < 4; j++) {
                float ql = lo16f(qv[j]), qh = hi16f(qv[j]);
                s0 += ql * lo16f(av[j]) + qh * hi16f(av[j]);
                s1 += ql * lo16f(bv_[j]) + qh * hi16f(bv_[j]);
            }
        }
        s0 += __shfl_xor(s0, 1);               // partner tid^1 holds the other 16 cols
        s1 += __shfl_xor(s1, 1);
        float mx = fmaxf(s0, s1);
        float p0 = __expf(s0 - mx), p1 = __expf(s1 - mx);
        float inv = 1.f / (p0 + p1);
        prob = make_float2(p0 * inv, p1 * inv);
    }
    __syncthreads();

    // ---- stage 3b: batched loads (4 frags), then V = oa_emb @ Wv + bv ----
    {
        short8 w3_0 = preV[OFF_WV / 8 + (wave * 4 + 0) * 64 + lane];
        short8 w3_1 = preV[OFF_WV / 8 + (wave * 4 + 1) * 64 + lane];
        short8 w3_2 = preV[OFF_WV / 8 + (wave * 4 + 2) * 64 + lane];
        short8 w3_3 = preV[OFF_WV / 8 + (wave * 4 + 3) * 64 + lane];
        float b3v = bv[wave * 16 + l15];
        int colv = wave * 16 + l15;
        for (int mt = 0; mt < 3; mt++) {
            short8 xa0 = *(const short8*)&s_oaemb[(mt * 16 + l15) * LDC + 0  + quad * 8];
            short8 xa1 = *(const short8*)&s_oaemb[(mt * 16 + l15) * LDC + 32 + quad * 8];
            short8 xa2 = *(const short8*)&s_oaemb[(mt * 16 + l15) * LDC + 64 + quad * 8];
            short8 xa3 = *(const short8*)&s_oaemb[(mt * 16 + l15) * LDC + 96 + quad * 8];
            floatx4 acc = {};
            acc = MFMA(xa0, w3_0, acc); acc = MFMA(xa1, w3_1, acc);
            acc = MFMA(xa2, w3_2, acc); acc = MFMA(xa3, w3_3, acc);
            #pragma unroll
            for (int rg = 0; rg < 4; rg++) {
                int m = mt * 16 + quad * 4 + rg;
                s_bufA[m * LDC + colv] = f2bf(acc[rg] + b3v);
            }
        }
    }
    __syncthreads();

    // ---- stage 3c: attn_out = probs @ V; 384 threads, each writes its 16-col half ----
    if (attn_thread) {
        const int co = h3 * HD + half3 * 16;
        const uint4* v0p = (const uint4*)&s_bufA[(e3 * NA + m30) * LDC + co];
        const uint4* v1p = (const uint4*)&s_bufA[(e3 * NA + m31) * LDC + co];
        uint4* dst = (uint4*)&s_oaemb[(e3 * NA + n3) * LDC + co];
        #pragma unroll
        for (int c = 0; c < 2; c++) {
            uint4 aw = v0p[c], bw = v1p[c], ow;
            u32 av[4] = {aw.x, aw.y, aw.z, aw.w};
            u32 bv_[4] = {bw.x, bw.y, bw.z, bw.w};
            u32 ov[4];
            #pragma unroll
            for (int j = 0; j < 4; j++) {
                float lo = prob.x * lo16f(av[j]) + prob.y * lo16f(bv_[j]);
                float hi = prob.x * hi16f(av[j]) + prob.y * hi16f(bv_[j]);
                ov[j] = pk_bf16(lo, hi);
            }
            ow.x = ov[0]; ow.y = ov[1]; ow.z = ov[2]; ow.w = ov[3];
            dst[c] = ow;
        }
    }
    __syncthreads();

    // ---- stage 4: critic layer 1, 3 jobs/wave; per-agent batches of 8 frags ----
    {
        int colc = wave * 16 + l15;
        float b4_0 = bc1[0 * HID + wave * 16 + l15];
        float b4_1 = bc1[1 * HID + wave * 16 + l15];
        float b4_2 = bc1[2 * HID + wave * 16 + l15];
        // agent 0
        {
            short8 w0 = preV[OFF_WC1 / 8 + 0 * 4096 + (wave * 8 + 0) * 64 + lane];
            short8 w1 = preV[OFF_WC1 / 8 + 0 * 4096 + (wave * 8 + 1) * 64 + lane];
            short8 w2 = preV[OFF_WC1 / 8 + 0 * 4096 + (wave * 8 + 2) * 64 + lane];
            short8 w3 = preV[OFF_WC1 / 8 + 0 * 4096 + (wave * 8 + 3) * 64 + lane];
            short8 w4 = preV[OFF_WC1 / 8 + 0 * 4096 + (wave * 8 + 4) * 64 + lane];
            short8 w5 = preV[OFF_WC1 / 8 + 0 * 4096 + (wave * 8 + 5) * 64 + lane];
            short8 w6 = preV[OFF_WC1 / 8 + 0 * 4096 + (wave * 8 + 6) * 64 + lane];
            short8 w7 = preV[OFF_WC1 / 8 + 0 * 4096 + (wave * 8 + 7) * 64 + lane];
            floatx4 acc = {};
            short8 a;
            a = *(const short8*)&s_oemb [(l15 * NA + 0) * LDC + 0  + quad * 8]; acc = MFMA(a, w0, acc);
            a = *(const short8*)&s_oemb [(l15 * NA + 0) * LDC + 32 + quad * 8]; acc = MFMA(a, w1, acc);
            a = *(const short8*)&s_oemb [(l15 * NA + 0) * LDC + 64 + quad * 8]; acc = MFMA(a, w2, acc);
            a = *(const short8*)&s_oemb [(l15 * NA + 0) * LDC + 96 + quad * 8]; acc = MFMA(a, w3, acc);
            a = *(const short8*)&s_oaemb[(l15 * NA + 0) * LDC + 0  + quad * 8]; acc = MFMA(a, w4, acc);
            a = *(const short8*)&s_oaemb[(l15 * NA + 0) * LDC + 32 + quad * 8]; acc = MFMA(a, w5, acc);
            a = *(const short8*)&s_oaemb[(l15 * NA + 0) * LDC + 64 + quad * 8]; acc = MFMA(a, w6, acc);
            a = *(const short8*)&s_oaemb[(l15 * NA + 0) * LDC + 96 + quad * 8]; acc = MFMA(a, w7, acc);
            #pragma unroll
            for (int rg = 0; rg < 4; rg++) {
                int m = quad * 4 + rg;
                s_bufB[(m * NA + 0) * LDC + colc] = f2bf(leaky(acc[rg] + b4_0));
            }
        }
        // agent 1
        {
            short8 w0 = preV[OFF_WC1 / 8 + 1 * 4096 + (wave * 8 + 0) * 64 + lane];
            short8 w1 = preV[OFF_WC1 / 8 + 1 * 4096 + (wave * 8 + 1) * 64 + lane];
            short8 w2 = preV[OFF_WC1 / 8 + 1 * 4096 + (wave * 8 + 2) * 64 + lane];
            short8 w3 = preV[OFF_WC1 / 8 + 1 * 4096 + (wave * 8 + 3) * 64 + lane];
            short8 w4 = preV[OFF_WC1 / 8 + 1 * 4096 + (wave * 8 + 4) * 64 + lane];
            short8 w5 = preV[OFF_WC1 / 8 + 1 * 4096 + (wave * 8 + 5) * 64 + lane];
            short8 w6 = preV[OFF_WC1 / 8 + 1 * 4096 + (wave * 8 + 6) * 64 + lane];
            short8 w7 = preV[OFF_WC1 / 8 + 1 * 4096 + (wave * 8 + 7) * 64 + lane];
            floatx4 acc = {};
            short8 a;
            a = *(const short8*)&s_oemb [(l15 * NA + 1) * LDC + 0  + quad * 8]; acc = MFMA(a, w0, acc);
            a = *(const short8*)&s_oemb [(l15 * NA + 1) * LDC + 32 + quad * 8]; acc = MFMA(a, w1, acc);
            a = *(const short8*)&s_oemb [(l15 * NA + 1) * LDC + 64 + quad * 8]; acc = MFMA(a, w2, acc);
            a = *(const short8*)&s_oemb [(l15 * NA + 1) * LDC + 96 + quad * 8]; acc = MFMA(a, w3, acc);
            a = *(const short8*)&s_oaemb[(l15 * NA + 1) * LDC + 0  + quad * 8]; acc = MFMA(a, w4, acc);
            a = *(const short8*)&s_oaemb[(l15 * NA + 1) * LDC + 32 + quad * 8]; acc = MFMA(a, w5, acc);
            a = *(const short8*)&s_oaemb[(l15 * NA + 1) * LDC + 64 + quad * 8]; acc = MFMA(a, w6, acc);
            a = *(const short8*)&s_oaemb[(l15 * NA + 1) * LDC + 96 + quad * 8]; acc = MFMA(a, w7, acc);
            #pragma unroll
            for (int rg = 0; rg < 4; rg++) {
                int m = quad * 4 + rg;
                s_bufB[(m * NA + 1) * LDC + colc] = f2bf(leaky(acc[rg] + b4_1));
            }
        }
        // agent 2
        {
            short8 w0 = preV[OFF_WC1 / 8 + 2 * 4096 + (wave * 8 + 0) * 64 + lane];
            short8 w1 = preV[OFF_WC1 / 8 + 2 * 4096 + (wave * 8 + 1) * 64 + lane];
            short8 w2 = preV[OFF_WC1 / 8 + 2 * 4096 + (wave * 8 + 2) * 64 + lane];
            short8 w3 = preV[OFF_WC1 / 8 + 2 * 4096 + (wave * 8 + 3) * 64 + lane];
            short8 w4 = preV[OFF_WC1 / 8 + 2 * 4096 + (wave * 8 + 4) * 64 + lane];
            short8 w5 = preV[OFF_WC1 / 8 + 2 * 4096 + (wave * 8 + 5) * 64 + lane];
            short8 w6 = preV[OFF_WC1 / 8 + 2 * 4096 + (wave * 8 + 6) * 64 + lane];
            short8 w7 = preV[OFF_WC1 / 8 + 2 * 4096 + (wave * 8 + 7) * 64 + lane];
            floatx4 acc = {};
            short8 a;
            a = *(const short8*)&s_oemb [(l15 * NA + 2) * LDC + 0  + quad * 8]; acc = MFMA(a, w0, acc);
            a = *(const short8*)&s_oemb [(l15 * NA + 2) * LDC + 32 + quad * 8]; acc = MFMA(a, w1, acc);
            a = *(const short8*)&s_oemb [(l15 * NA + 2) * LDC + 64 + quad * 8]; acc = MFMA(a, w2, acc);
            a = *(const short8*)&s_oemb [(l15 * NA + 2) * LDC + 96 + quad * 8]; acc = MFMA(a, w3, acc);
            a = *(const short8*)&s_oaemb[(l15 * NA + 2) * LDC + 0  + quad * 8]; acc = MFMA(a, w4, acc);
            a = *(const short8*)&s_oaemb[(l15 * NA + 2) * LDC + 32 + quad * 8]; acc = MFMA(a, w5, acc);
            a = *(const short8*)&s_oaemb[(l15 * NA + 2) * LDC + 64 + quad * 8]; acc = MFMA(a, w6, acc);
            a = *(const short8*)&s_oaemb[(l15 * NA + 2) * LDC + 96 + quad * 8]; acc = MFMA(a, w7, acc);
            #pragma unroll
            for (int rg = 0; rg < 4; rg++) {
                int m = quad * 4 + rg;
                s_bufB[(m * NA + 2) * LDC + colc] = f2bf(leaky(acc[rg] + b4_2));
            }
        }
    }
    __syncthreads();

    // ---- stage 5: critic layer 2 -> q_values, f32 out (batched 4-frag load) ----
    if (wave < NA) {
        int agent = wave;
        short8 w5_0 = preV[OFF_WC2 / 8 + agent * 256 + 0 * 64 + lane];
        short8 w5_1 = preV[OFF_WC2 / 8 + agent * 256 + 1 * 64 + lane];
        short8 w5_2 = preV[OFF_WC2 / 8 + agent * 256 + 2 * 64 + lane];
        short8 w5_3 = preV[OFF_WC2 / 8 + agent * 256 + 3 * 64 + lane];
        floatx4 acc = {};
        short8 a;
        a = *(const short8*)&s_bufB[(l15 * NA + agent) * LDC + 0  + quad * 8]; acc = MFMA(a, w5_0, acc);
        a = *(const short8*)&s_bufB[(l15 * NA + agent) * LDC + 32 + quad * 8]; acc = MFMA(a, w5_1, acc);
        a = *(const short8*)&s_bufB[(l15 * NA + agent) * LDC + 64 + quad * 8]; acc = MFMA(a, w5_2, acc);
        a = *(const short8*)&s_bufB[(l15 * NA + agent) * LDC + 96 + quad * 8]; acc = MFMA(a, w5_3, acc);
        if (l15 < ACTD) {
            float b5v = bc2[agent * ACTD + l15];
            #pragma unroll
            for (int rg = 0; rg < 4; rg++) {
                int m = quad * 4 + rg;
                out[((b0 + m) * NA + agent) * ACTD + l15] = acc[rg] + b5v;
            }
        }
    }
}

extern "C" void kernel_launch(void* const* d_in, const int* in_sizes, int n_in,
                              void* d_out, int out_size, void* d_ws, size_t ws_size,
                              hipStream_t stream) {
    const float* obs = (const float*)d_in[0];
    const float* act = (const float*)d_in[1];
    const float* Wo  = (const float*)d_in[2];
    const float* bo  = (const float*)d_in[3];
    const float* Woa = (const float*)d_in[4];
    const float* boa = (const float*)d_in[5];
    const float* Wq  = (const float*)d_in[6];
    const float* bq  = (const float*)d_in[7];
    const float* Wk  = (const float*)d_in[8];
    const float* bk  = (const float*)d_in[9];
    const float* Wv  = (const float*)d_in[10];
    const float* bv  = (const float*)d_in[11];
    const float* Wc1 = (const float*)d_in[12];
    const float* bc1 = (const float*)d_in[13];
    const float* Wc2 = (const float*)d_in[14];
    const float* bc2 = (const float*)d_in[15];
    u16* pre = (u16*)d_ws;   // needs 380928 B of workspace

    prepack_kernel<<<(PRE_TOTAL + 255) / 256, 256, 0, stream>>>(Wo, Woa, Wq, Wk, Wv, Wc1, Wc2, pre);
    fused_kernel<<<BATCH / MB, NTHREADS, 0, stream>>>(obs, act, bo, boa, bq, bk, bv, bc1, bc2, pre,
                                                      (float*)d_out);
}